// Round 3
// baseline (539.989 us; speedup 1.0000x reference)
//
#include <hip/hip_runtime.h>
#include <hip/hip_bf16.h>

typedef unsigned short u16;
typedef short s16x8 __attribute__((ext_vector_type(8)));
typedef float f32x4 __attribute__((ext_vector_type(4)));

#define F_DIM 2048
#define A_DIM 1024
#define H_DIM 1024
#define BATCH 128
#define LLEN  196
#define MROWS (BATCH * LLEN)   // 25088
#define LDA   40               // fallback kernel's padded LDS stride

__device__ __forceinline__ u16 f2b(float x) {
  union { float f; unsigned int u; } c; c.f = x;
  unsigned int r = (c.u + 0x7fffu + ((c.u >> 16) & 1u)) >> 16;  // RNE
  return (u16)r;
}

__device__ __forceinline__ float b2f(u16 x) {
  union { unsigned int u; float f; } c; c.u = ((unsigned int)x) << 16;
  return c.f;
}

__device__ __forceinline__ void gload_lds16(const void* g, void* l) {
  __builtin_amdgcn_global_load_lds((const __attribute__((address_space(1))) void*)g,
                                   (__attribute__((address_space(3))) void*)l, 16, 0, 0);
}

// ---------------------------------------------------------------------------
// K0a: W_enc (2048x1024 fp32, k-major) -> WT (1024x2048 bf16, a-major)
__global__ void wenc_cvt_kernel(const float* __restrict__ W, u16* __restrict__ WT) {
  __shared__ float tile[32][33];
  int kb = blockIdx.x * 32, ab = blockIdx.y * 32;
  int t = threadIdx.x;
  int r = t >> 3, c = (t & 7) * 4;
  float4 v = *(const float4*)&W[(size_t)(kb + r) * A_DIM + ab + c];
  tile[r][c] = v.x; tile[r][c + 1] = v.y; tile[r][c + 2] = v.z; tile[r][c + 3] = v.w;
  __syncthreads();
  ushort4 o;
  o.x = f2b(tile[c + 0][r]);
  o.y = f2b(tile[c + 1][r]);
  o.z = f2b(tile[c + 2][r]);
  o.w = f2b(tile[c + 3][r]);
  *(ushort4*)&WT[(size_t)(ab + r) * F_DIM + kb + c] = o;
}

// ---------------------------------------------------------------------------
// K0b: enc fp32 -> bf16 (25088x2048)
__global__ void enc_cvt_kernel(const float* __restrict__ enc, u16* __restrict__ encb) {
  int idx = blockIdx.x * 256 + threadIdx.x;
  const float4* src = (const float4*)enc;
  uint4* dst = (uint4*)encb;
  #pragma unroll
  for (int it = 0; it < 8; ++it) {
    size_t p = (size_t)idx + (size_t)it * 802816;
    float4 v0 = src[p * 2], v1 = src[p * 2 + 1];
    union { u16 u[8]; uint4 q; } o;
    o.u[0] = f2b(v0.x); o.u[1] = f2b(v0.y); o.u[2] = f2b(v0.z); o.u[3] = f2b(v0.w);
    o.u[4] = f2b(v1.x); o.u[5] = f2b(v1.y); o.u[6] = f2b(v1.z); o.u[7] = f2b(v1.w);
    dst[p] = o.q;
  }
}

// ---------------------------------------------------------------------------
// K1: attn2p[b][a] = hidden[b]·W_hid[:,a] + b_hid[a] + b_enc[a]   (k-split, atomic)
__global__ void attn2_kernel(const float* __restrict__ hidden, const float* __restrict__ W_hid,
                             const float* __restrict__ b_hid, const float* __restrict__ b_enc,
                             float* __restrict__ attn2p) {
  __shared__ float hl[8][256];
  int t = threadIdx.x;
  int a  = blockIdx.x * 256 + t;
  int b0 = blockIdx.y * 8;
  int k0 = blockIdx.z * 256;
  {
    int j = t >> 5, kk = (t & 31) * 8;
    float4 v0 = *(const float4*)&hidden[(size_t)(b0 + j) * H_DIM + k0 + kk];
    float4 v1 = *(const float4*)&hidden[(size_t)(b0 + j) * H_DIM + k0 + kk + 4];
    hl[j][kk + 0] = v0.x; hl[j][kk + 1] = v0.y; hl[j][kk + 2] = v0.z; hl[j][kk + 3] = v0.w;
    hl[j][kk + 4] = v1.x; hl[j][kk + 5] = v1.y; hl[j][kk + 6] = v1.z; hl[j][kk + 7] = v1.w;
  }
  __syncthreads();
  float acc[8] = {0.f, 0.f, 0.f, 0.f, 0.f, 0.f, 0.f, 0.f};
  #pragma unroll 4
  for (int k = 0; k < 256; ++k) {
    float w = W_hid[(size_t)(k0 + k) * A_DIM + a];
    #pragma unroll
    for (int j = 0; j < 8; ++j) acc[j] = fmaf(hl[j][k], w, acc[j]);
  }
  if (blockIdx.z == 0) {
    float bias = b_hid[a] + b_enc[a];
    #pragma unroll
    for (int j = 0; j < 8; ++j) acc[j] += bias;
  }
  #pragma unroll
  for (int j = 0; j < 8; ++j) atomicAdd(&attn2p[(size_t)(b0 + j) * A_DIM + a], acc[j]);
}

// ---------------------------------------------------------------------------
// K2 (primary): bf16 MFMA GEMM, m97 structure + XCD-aware 1D grid swizzle.
// Grid 1600 = 25 groups x (8 n x 8 m). All 8 n-tile blocks sharing an A-tile
// have identical id%8 -> same XCD -> A staged once per XCD L2.
__global__ void gemm_score_bf16(const u16* __restrict__ encb, const u16* __restrict__ WT,
                                const float* __restrict__ attn2p, const float* __restrict__ W_full,
                                float* __restrict__ scores) {
  __shared__ __align__(16) u16 As[128 * 32];
  __shared__ __align__(16) u16 Bs[128 * 32];
  __shared__ float wf_lds[128];
  __shared__ float at2_lds[2][128];

  int i = blockIdx.x;
  int g  = i >> 6;
  int r  = i & 63;
  int y  = r >> 3;         // n-tile 0..7
  int gi = r & 7;          // m-tile within group == i%8 == XCD residue
  int mt = g * 8 + gi;
  if (mt >= MROWS / 128) return;

  int n0 = y * 128;
  int m0 = mt * 128;
  int t = threadIdx.x;

  int b0 = m0 / LLEN;
  int bnd = (b0 + 1) * LLEN;
  int b1 = min(b0 + 1, BATCH - 1);

  if (t < 128) {
    wf_lds[t] = W_full[n0 + t];
    at2_lds[0][t] = attn2p[(size_t)b0 * A_DIM + n0 + t];
    at2_lds[1][t] = attn2p[(size_t)b1 * A_DIM + n0 + t];
  }

  int lane = t & 63, wave = t >> 6;
  int wr = wave >> 1, wc = wave & 1;
  int c16 = lane & 15, quad = lane >> 4;

  f32x4 acc[4][4];
  #pragma unroll
  for (int ii = 0; ii < 4; ++ii)
    #pragma unroll
    for (int j = 0; j < 4; ++j) acc[ii][j] = (f32x4){0.f, 0.f, 0.f, 0.f};

  const u16* agp0 = encb + (size_t)(m0 + (t >> 2)) * F_DIM + (t & 3) * 8;
  const u16* agp1 = agp0 + (size_t)64 * F_DIM;
  const u16* bgp0 = WT + (size_t)(n0 + (t >> 2)) * F_DIM + (t & 3) * 8;
  const u16* bgp1 = bgp0 + (size_t)64 * F_DIM;
  u16* al = As + wave * 512;
  u16* bl = Bs + wave * 512;

  for (int kt = 0; kt < F_DIM; kt += 32) {
    gload_lds16(agp0 + kt, al);
    gload_lds16(agp1 + kt, al + 2048);
    gload_lds16(bgp0 + kt, bl);
    gload_lds16(bgp1 + kt, bl + 2048);
    __syncthreads();
    s16x8 af[4], bf[4];
    #pragma unroll
    for (int ii = 0; ii < 4; ++ii) {
      af[ii] = *(const s16x8*)&As[(wr * 64 + ii * 16 + c16) * 32 + quad * 8];
      bf[ii] = *(const s16x8*)&Bs[(wc * 64 + ii * 16 + c16) * 32 + quad * 8];
    }
    #pragma unroll
    for (int mi = 0; mi < 4; ++mi)
      #pragma unroll
      for (int ni = 0; ni < 4; ++ni)
        acc[mi][ni] = __builtin_amdgcn_mfma_f32_16x16x32_bf16(af[mi], bf[ni], acc[mi][ni], 0, 0, 0);
    __syncthreads();
  }

  float wf[4], a2a[4], a2b[4];
  #pragma unroll
  for (int ni = 0; ni < 4; ++ni) {
    int col = wc * 64 + ni * 16 + c16;
    wf[ni] = wf_lds[col];
    a2a[ni] = at2_lds[0][col];
    a2b[ni] = at2_lds[1][col];
  }
  #pragma unroll
  for (int mi = 0; mi < 4; ++mi) {
    #pragma unroll
    for (int rr = 0; rr < 4; ++rr) {
      int row_g = m0 + wr * 64 + mi * 16 + quad * 4 + rr;
      bool hi = row_g >= bnd;
      float p = 0.f;
      #pragma unroll
      for (int ni = 0; ni < 4; ++ni) {
        float v = acc[mi][ni][rr] + (hi ? a2b[ni] : a2a[ni]);
        v = fmaxf(v, 0.f);
        p = fmaf(v, wf[ni], p);
      }
      p += __shfl_xor(p, 1);
      p += __shfl_xor(p, 2);
      p += __shfl_xor(p, 4);
      p += __shfl_xor(p, 8);
      if (c16 == 0) atomicAdd(&scores[row_g], p);
    }
  }
}

// ---------------------------------------------------------------------------
// K2 (fallback): fp32-staging GEMM — used only if ws_size too small
__global__ void gemm_score_f32(const float* __restrict__ enc, const u16* __restrict__ WT,
                               const float* __restrict__ attn2p, const float* __restrict__ W_full,
                               float* __restrict__ scores) {
  __shared__ __align__(16) u16 As[128 * LDA];
  __shared__ __align__(16) u16 Bs[128 * LDA];
  __shared__ float wf_lds[128];
  __shared__ float at2_lds[2][128];

  int n0 = blockIdx.x * 128;
  int m0 = blockIdx.y * 128;
  int t = threadIdx.x;
  int b0 = m0 / LLEN;
  int bnd = (b0 + 1) * LLEN;
  int b1 = min(b0 + 1, BATCH - 1);
  if (t < 128) {
    wf_lds[t] = W_full[n0 + t];
    at2_lds[0][t] = attn2p[(size_t)b0 * A_DIM + n0 + t];
    at2_lds[1][t] = attn2p[(size_t)b1 * A_DIM + n0 + t];
  }
  int lane = t & 63, wave = t >> 6;
  int wr = wave >> 1, wc = wave & 1;
  int c16 = lane & 15, quad = lane >> 4;
  f32x4 acc[4][4];
  #pragma unroll
  for (int i = 0; i < 4; ++i)
    #pragma unroll
    for (int j = 0; j < 4; ++j) acc[i][j] = (f32x4){0.f, 0.f, 0.f, 0.f};
  int ar = t >> 3, ac = (t & 7) * 4;
  int br = t >> 2, bc = (t & 3) * 8;
  const float* ap = enc + (size_t)(m0 + ar) * F_DIM + ac;
  const u16*  bp = WT + (size_t)(n0 + br) * F_DIM + bc;
  for (int kt = 0; kt < F_DIM; kt += 32) {
    #pragma unroll
    for (int p = 0; p < 4; ++p) {
      float4 v = *(const float4*)(ap + (size_t)p * 32 * F_DIM + kt);
      ushort4 u;
      u.x = f2b(v.x); u.y = f2b(v.y); u.z = f2b(v.z); u.w = f2b(v.w);
      *(ushort4*)&As[(ar + p * 32) * LDA + ac] = u;
    }
    #pragma unroll
    for (int p = 0; p < 2; ++p) {
      uint4 v = *(const uint4*)(bp + (size_t)p * 64 * F_DIM + kt);
      *(uint4*)&Bs[(br + p * 64) * LDA + bc] = v;
    }
    __syncthreads();
    s16x8 af[4], bf[4];
    #pragma unroll
    for (int i = 0; i < 4; ++i) {
      af[i] = *(const s16x8*)&As[(wr * 64 + i * 16 + c16) * LDA + quad * 8];
      bf[i] = *(const s16x8*)&Bs[(wc * 64 + i * 16 + c16) * LDA + quad * 8];
    }
    #pragma unroll
    for (int mi = 0; mi < 4; ++mi)
      #pragma unroll
      for (int ni = 0; ni < 4; ++ni)
        acc[mi][ni] = __builtin_amdgcn_mfma_f32_16x16x32_bf16(af[mi], bf[ni], acc[mi][ni], 0, 0, 0);
    __syncthreads();
  }
  float wf[4], a2a[4], a2b[4];
  #pragma unroll
  for (int ni = 0; ni < 4; ++ni) {
    int col = wc * 64 + ni * 16 + c16;
    wf[ni] = wf_lds[col];
    a2a[ni] = at2_lds[0][col];
    a2b[ni] = at2_lds[1][col];
  }
  #pragma unroll
  for (int mi = 0; mi < 4; ++mi) {
    #pragma unroll
    for (int r = 0; r < 4; ++r) {
      int row_g = m0 + wr * 64 + mi * 16 + quad * 4 + r;
      bool hi = row_g >= bnd;
      float p = 0.f;
      #pragma unroll
      for (int ni = 0; ni < 4; ++ni) {
        float v = acc[mi][ni][r] + (hi ? a2b[ni] : a2a[ni]);
        v = fmaxf(v, 0.f);
        p = fmaf(v, wf[ni], p);
      }
      p += __shfl_xor(p, 1);
      p += __shfl_xor(p, 2);
      p += __shfl_xor(p, 4);
      p += __shfl_xor(p, 8);
      if (c16 == 0) atomicAdd(&scores[row_g], p);
    }
  }
}

// ---------------------------------------------------------------------------
// K3: softmax over L=196 per batch row (b_full dropped: softmax-invariant)
__global__ void softmax_kernel(const float* __restrict__ scores, float* __restrict__ alpha) {
  __shared__ float red[8];
  int b = blockIdx.x, t = threadIdx.x;
  float s = (t < LLEN) ? scores[b * LLEN + t] : -3.0e38f;
  float m = s;
  #pragma unroll
  for (int o = 1; o <= 32; o <<= 1) m = fmaxf(m, __shfl_xor(m, o));
  if ((t & 63) == 0) red[t >> 6] = m;
  __syncthreads();
  m = fmaxf(fmaxf(red[0], red[1]), fmaxf(red[2], red[3]));
  float e = (t < LLEN) ? expf(s - m) : 0.f;
  float sum = e;
  #pragma unroll
  for (int o = 1; o <= 32; o <<= 1) sum += __shfl_xor(sum, o);
  __syncthreads();
  if ((t & 63) == 0) red[4 + (t >> 6)] = sum;
  __syncthreads();
  sum = red[4] + red[5] + red[6] + red[7];
  if (t < LLEN) alpha[b * LLEN + t] = e / sum;
}

// ---------------------------------------------------------------------------
// K4 (primary): context from bf16 encb. Grid (7 L-chunks of 28, 128 batches).
__global__ void context_bf16_kernel(const u16* __restrict__ encb, const float* __restrict__ alpha,
                                    float* __restrict__ out) {
  __shared__ float al[28];
  int b = blockIdx.y, t = threadIdx.x;
  int l0 = blockIdx.x * 28;
  if (t < 28) al[t] = alpha[b * LLEN + l0 + t];
  __syncthreads();
  const uint4* e4 = (const uint4*)(encb + ((size_t)b * LLEN + l0) * F_DIM) + t;
  float acc[8] = {0.f, 0.f, 0.f, 0.f, 0.f, 0.f, 0.f, 0.f};
  #pragma unroll 4
  for (int l = 0; l < 28; ++l) {
    uint4 v = e4[(size_t)l * (F_DIM / 8)];
    float a = al[l];
    const u16* u = (const u16*)&v;
    #pragma unroll
    for (int j = 0; j < 8; ++j) acc[j] = fmaf(b2f(u[j]), a, acc[j]);
  }
  float* o = out + (size_t)b * F_DIM + t * 8;
  #pragma unroll
  for (int j = 0; j < 8; ++j) atomicAdd(o + j, acc[j]);
}

// K4 (fallback): fp32 context, L split 4x49
__global__ void context_kernel(const float* __restrict__ enc, const float* __restrict__ alpha,
                               float* __restrict__ out) {
  __shared__ float al[49];
  int b = blockIdx.y, t = threadIdx.x;
  int l0 = blockIdx.z * 49;
  int f4 = blockIdx.x * 256 + t;
  if (t < 49) al[t] = alpha[b * LLEN + l0 + t];
  __syncthreads();
  const float4* e4 = (const float4*)enc + ((size_t)b * LLEN + l0) * (F_DIM / 4) + f4;
  float4 acc = {0.f, 0.f, 0.f, 0.f};
  #pragma unroll 7
  for (int l = 0; l < 49; ++l) {
    float4 v = e4[(size_t)l * (F_DIM / 4)];
    float a = al[l];
    acc.x = fmaf(v.x, a, acc.x);
    acc.y = fmaf(v.y, a, acc.y);
    acc.z = fmaf(v.z, a, acc.z);
    acc.w = fmaf(v.w, a, acc.w);
  }
  float* o = out + (size_t)b * F_DIM + f4 * 4;
  atomicAdd(o + 0, acc.x);
  atomicAdd(o + 1, acc.y);
  atomicAdd(o + 2, acc.z);
  atomicAdd(o + 3, acc.w);
}

// ---------------------------------------------------------------------------
extern "C" void kernel_launch(void* const* d_in, const int* in_sizes, int n_in,
                              void* d_out, int out_size, void* d_ws, size_t ws_size,
                              hipStream_t stream) {
  const float* enc    = (const float*)d_in[0];
  const float* hidden = (const float*)d_in[1];
  const float* W_enc  = (const float*)d_in[2];
  const float* b_enc  = (const float*)d_in[3];
  const float* W_hid  = (const float*)d_in[4];
  const float* b_hid  = (const float*)d_in[5];
  const float* W_full = (const float*)d_in[6];
  float* out = (float*)d_out;
  float* alpha_out = out + (size_t)BATCH * F_DIM;

  const size_t encb_bytes = (size_t)MROWS * F_DIM * sizeof(u16);     // 102.8 MB
  const size_t wt_bytes   = (size_t)A_DIM * F_DIM * sizeof(u16);     // 4 MB
  const size_t a2_bytes   = (size_t)BATCH * A_DIM * sizeof(float);   // 512 KB
  const size_t sc_bytes   = (size_t)MROWS * sizeof(float);           // 100 KB
  char* ws = (char*)d_ws;

  if (ws_size >= encb_bytes + wt_bytes + a2_bytes + sc_bytes) {
    u16*   encb   = (u16*)ws;
    u16*   WT     = (u16*)(ws + encb_bytes);
    float* attn2p = (float*)(ws + encb_bytes + wt_bytes);
    float* scores = (float*)(ws + encb_bytes + wt_bytes + a2_bytes);

    hipMemsetAsync(attn2p, 0, a2_bytes, stream);
    hipMemsetAsync(scores, 0, sc_bytes, stream);
    hipMemsetAsync(out, 0, (size_t)BATCH * F_DIM * sizeof(float), stream);

    wenc_cvt_kernel<<<dim3(F_DIM / 32, A_DIM / 32), 256, 0, stream>>>(W_enc, WT);
    enc_cvt_kernel<<<dim3(3136), 256, 0, stream>>>(enc, encb);
    attn2_kernel<<<dim3(A_DIM / 256, BATCH / 8, 4), 256, 0, stream>>>(hidden, W_hid, b_hid, b_enc, attn2p);
    gemm_score_bf16<<<dim3(1600), 256, 0, stream>>>(encb, WT, attn2p, W_full, scores);
    softmax_kernel<<<dim3(BATCH), 256, 0, stream>>>(scores, alpha_out);
    context_bf16_kernel<<<dim3(7, BATCH), 256, 0, stream>>>(encb, alpha_out, out);
  } else {
    u16*   WT     = (u16*)ws;
    float* attn2p = (float*)(ws + wt_bytes);
    float* scores = (float*)(ws + wt_bytes + a2_bytes);

    hipMemsetAsync(attn2p, 0, a2_bytes, stream);
    hipMemsetAsync(scores, 0, sc_bytes, stream);
    hipMemsetAsync(out, 0, (size_t)BATCH * F_DIM * sizeof(float), stream);

    wenc_cvt_kernel<<<dim3(F_DIM / 32, A_DIM / 32), 256, 0, stream>>>(W_enc, WT);
    attn2_kernel<<<dim3(A_DIM / 256, BATCH / 8, 4), 256, 0, stream>>>(hidden, W_hid, b_hid, b_enc, attn2p);
    gemm_score_f32<<<dim3(A_DIM / 128, MROWS / 128), 256, 0, stream>>>(enc, WT, attn2p, W_full, scores);
    softmax_kernel<<<dim3(BATCH), 256, 0, stream>>>(scores, alpha_out);
    context_kernel<<<dim3(F_DIM / 4 / 256, BATCH, 4), 256, 0, stream>>>(enc, alpha_out, out);
  }
}

// Round 4
// 500.155 us; speedup vs baseline: 1.0796x; 1.0796x over previous
//
#include <hip/hip_runtime.h>
#include <hip/hip_bf16.h>

typedef unsigned short u16;
typedef short s16x8 __attribute__((ext_vector_type(8)));
typedef unsigned int u32x4 __attribute__((ext_vector_type(4)));
typedef float f32x4 __attribute__((ext_vector_type(4)));

#define F_DIM 2048
#define A_DIM 1024
#define H_DIM 1024
#define BATCH 128
#define LLEN  196
#define MROWS (BATCH * LLEN)   // 25088

__device__ __forceinline__ u16 f2b(float x) {
  union { float f; unsigned int u; } c; c.f = x;
  unsigned int r = (c.u + 0x7fffu + ((c.u >> 16) & 1u)) >> 16;  // RNE
  return (u16)r;
}

// gfx950-native packed fp32->bf16 (RNE): dst.lo16 = cvt(a), dst.hi16 = cvt(b)
__device__ __forceinline__ unsigned int f2b_pk(float a, float b) {
  unsigned int r;
  asm volatile("v_cvt_pk_bf16_f32 %0, %1, %2" : "=v"(r) : "v"(a), "v"(b));
  return r;
}

__device__ __forceinline__ void gload_lds16(const void* g, void* l) {
  __builtin_amdgcn_global_load_lds((const __attribute__((address_space(1))) void*)g,
                                   (__attribute__((address_space(3))) void*)l, 16, 0, 0);
}

// ---------------------------------------------------------------------------
// K0: W_enc (2048x1024 fp32, k-major) -> WT (1024x2048 bf16, a-major)
__global__ void wenc_cvt_kernel(const float* __restrict__ W, u16* __restrict__ WT) {
  __shared__ float tile[32][33];
  int kb = blockIdx.x * 32, ab = blockIdx.y * 32;
  int t = threadIdx.x;
  int r = t >> 3, c = (t & 7) * 4;
  float4 v = *(const float4*)&W[(size_t)(kb + r) * A_DIM + ab + c];
  tile[r][c] = v.x; tile[r][c + 1] = v.y; tile[r][c + 2] = v.z; tile[r][c + 3] = v.w;
  __syncthreads();
  ushort4 o;
  o.x = f2b(tile[c + 0][r]);
  o.y = f2b(tile[c + 1][r]);
  o.z = f2b(tile[c + 2][r]);
  o.w = f2b(tile[c + 3][r]);
  *(ushort4*)&WT[(size_t)(ab + r) * F_DIM + kb + c] = o;
}

// ---------------------------------------------------------------------------
// K1: attn2p[b][a] = hidden[b]·W_hid[:,a] + b_hid[a] + b_enc[a]  (k-split 8, atomic)
__global__ void attn2_kernel(const float* __restrict__ hidden, const float* __restrict__ W_hid,
                             const float* __restrict__ b_hid, const float* __restrict__ b_enc,
                             float* __restrict__ attn2p) {
  __shared__ float hl[8][128];
  int t = threadIdx.x;
  int a  = blockIdx.x * 256 + t;
  int b0 = blockIdx.y * 8;
  int k0 = blockIdx.z * 128;
  {
    int j = t >> 5, kk = (t & 31) * 4;
    float4 v = *(const float4*)&hidden[(size_t)(b0 + j) * H_DIM + k0 + kk];
    hl[j][kk + 0] = v.x; hl[j][kk + 1] = v.y; hl[j][kk + 2] = v.z; hl[j][kk + 3] = v.w;
  }
  __syncthreads();
  float acc[8] = {0.f, 0.f, 0.f, 0.f, 0.f, 0.f, 0.f, 0.f};
  #pragma unroll 4
  for (int k = 0; k < 128; ++k) {
    float w = W_hid[(size_t)(k0 + k) * A_DIM + a];
    #pragma unroll
    for (int j = 0; j < 8; ++j) acc[j] = fmaf(hl[j][k], w, acc[j]);
  }
  if (blockIdx.z == 0) {
    float bias = b_hid[a] + b_enc[a];
    #pragma unroll
    for (int j = 0; j < 8; ++j) acc[j] += bias;
  }
  #pragma unroll
  for (int j = 0; j < 8; ++j) atomicAdd(&attn2p[(size_t)(b0 + j) * A_DIM + a], acc[j]);
}

// ---------------------------------------------------------------------------
// K2: fused GEMM. A staged as fp32 via global_load_lds (no pre-cast pass);
// fp32->bf16 via v_cvt_pk_bf16_f32 in fragment assembly. XOR bank swizzle on
// both LDS tiles (implemented by permuting each lane's GLOBAL source, since
// global_load_lds forces dest = wave base + lane*16B): A keyed by row&7,
// B keyed by (row>>1)&3 -> conflict-free ds_read_b128 on both operands.
// XCD-aware 1D grid: 1600 = 25 groups x (8 n x 8 m); 8 blocks sharing an
// A-tile have identical id%8 -> same XCD L2.
__global__ void gemm_score(const float* __restrict__ enc, const u16* __restrict__ WT,
                           const float* __restrict__ attn2p, const float* __restrict__ W_full,
                           float* __restrict__ scores) {
  __shared__ __align__(16) float Asf[128 * 32];   // 16 KB fp32 A-tile
  __shared__ __align__(16) u16 Bs[128 * 32];      // 8 KB bf16 B-tile
  __shared__ float wf_lds[128];
  __shared__ float at2_lds[2][128];

  int i = blockIdx.x;
  int g  = i >> 6;
  int r  = i & 63;
  int y  = r >> 3;         // n-tile 0..7
  int gi = r & 7;          // m-tile within group == i%8 == XCD residue
  int mt = g * 8 + gi;
  if (mt >= MROWS / 128) return;

  int n0 = y * 128;
  int m0 = mt * 128;
  int t = threadIdx.x;

  int b0 = m0 / LLEN;
  int bnd = (b0 + 1) * LLEN;
  int b1 = min(b0 + 1, BATCH - 1);

  if (t < 128) {
    wf_lds[t] = W_full[n0 + t];
    at2_lds[0][t] = attn2p[(size_t)b0 * A_DIM + n0 + t];
    at2_lds[1][t] = attn2p[(size_t)b1 * A_DIM + n0 + t];
  }

  int lane = t & 63, wave = t >> 6;
  int wr = wave >> 1, wc = wave & 1;
  int c16 = lane & 15, quad = lane >> 4;

  f32x4 acc[4][4];
  #pragma unroll
  for (int ii = 0; ii < 4; ++ii)
    #pragma unroll
    for (int j = 0; j < 4; ++j) acc[ii][j] = (f32x4){0.f, 0.f, 0.f, 0.f};

  // A staging: wave covers rows wave*32..+31, 4 calls of 8 rows. Lane covers
  // row wave*32+p*8+(lane>>3), 4 floats at swizzled col ((lane&7)^((lane>>3)&7))*4.
  const float* agp = enc + (size_t)(m0 + wave * 32 + (lane >> 3)) * F_DIM
                         + ((lane & 7) ^ ((lane >> 3) & 7)) * 4;
  float* al = Asf + wave * 1024;   // floats; +p*256 per call
  // B staging: 2 calls of 64 rows (block-wide). Lane covers row t>>2,
  // 8 bf16 at swizzled col ((t&3)^((t>>3)&3))*8.
  const u16* bgp = WT + (size_t)(n0 + (t >> 2)) * F_DIM + ((t & 3) ^ ((t >> 3) & 3)) * 8;
  u16* bl = Bs + wave * 512;

  int akey = c16 & 7;          // A read swizzle key (row&7)
  int bkey = (c16 >> 1) & 3;   // B read swizzle key ((row>>1)&3)

  for (int kt = 0; kt < F_DIM; kt += 32) {
    gload_lds16(agp + kt, al);
    gload_lds16(agp + (size_t)8 * F_DIM + kt, al + 256);
    gload_lds16(agp + (size_t)16 * F_DIM + kt, al + 512);
    gload_lds16(agp + (size_t)24 * F_DIM + kt, al + 768);
    gload_lds16(bgp + kt, bl);
    gload_lds16(bgp + (size_t)64 * F_DIM + kt, bl + 2048);
    __syncthreads();
    s16x8 af[4], bf[4];
    #pragma unroll
    for (int ii = 0; ii < 4; ++ii) {
      int arow = (wr * 64 + ii * 16 + c16) * 32;
      float4 lo = *(const float4*)&Asf[arow + ((2 * quad) ^ akey) * 4];
      float4 hi = *(const float4*)&Asf[arow + ((2 * quad + 1) ^ akey) * 4];
      u32x4 w;
      w.x = f2b_pk(lo.x, lo.y);
      w.y = f2b_pk(lo.z, lo.w);
      w.z = f2b_pk(hi.x, hi.y);
      w.w = f2b_pk(hi.z, hi.w);
      af[ii] = __builtin_bit_cast(s16x8, w);
      bf[ii] = *(const s16x8*)&Bs[(wc * 64 + ii * 16 + c16) * 32 + (quad ^ bkey) * 8];
    }
    #pragma unroll
    for (int mi = 0; mi < 4; ++mi)
      #pragma unroll
      for (int ni = 0; ni < 4; ++ni)
        acc[mi][ni] = __builtin_amdgcn_mfma_f32_16x16x32_bf16(af[mi], bf[ni], acc[mi][ni], 0, 0, 0);
    __syncthreads();
  }

  float wf[4], a2a[4], a2b[4];
  #pragma unroll
  for (int ni = 0; ni < 4; ++ni) {
    int col = wc * 64 + ni * 16 + c16;
    wf[ni] = wf_lds[col];
    a2a[ni] = at2_lds[0][col];
    a2b[ni] = at2_lds[1][col];
  }
  #pragma unroll
  for (int mi = 0; mi < 4; ++mi) {
    #pragma unroll
    for (int rr = 0; rr < 4; ++rr) {
      int row_g = m0 + wr * 64 + mi * 16 + quad * 4 + rr;
      bool hi = row_g >= bnd;
      float p = 0.f;
      #pragma unroll
      for (int ni = 0; ni < 4; ++ni) {
        float v = acc[mi][ni][rr] + (hi ? a2b[ni] : a2a[ni]);
        v = fmaxf(v, 0.f);
        p = fmaf(v, wf[ni], p);
      }
      p += __shfl_xor(p, 1);
      p += __shfl_xor(p, 2);
      p += __shfl_xor(p, 4);
      p += __shfl_xor(p, 8);
      if (c16 == 0) atomicAdd(&scores[row_g], p);
    }
  }
}

// ---------------------------------------------------------------------------
// K3: softmax over L=196 per batch row (b_full dropped: softmax-invariant)
__global__ void softmax_kernel(const float* __restrict__ scores, float* __restrict__ alpha) {
  __shared__ float red[8];
  int b = blockIdx.x, t = threadIdx.x;
  float s = (t < LLEN) ? scores[b * LLEN + t] : -3.0e38f;
  float m = s;
  #pragma unroll
  for (int o = 1; o <= 32; o <<= 1) m = fmaxf(m, __shfl_xor(m, o));
  if ((t & 63) == 0) red[t >> 6] = m;
  __syncthreads();
  m = fmaxf(fmaxf(red[0], red[1]), fmaxf(red[2], red[3]));
  float e = (t < LLEN) ? expf(s - m) : 0.f;
  float sum = e;
  #pragma unroll
  for (int o = 1; o <= 32; o <<= 1) sum += __shfl_xor(sum, o);
  __syncthreads();
  if ((t & 63) == 0) red[4 + (t >> 6)] = sum;
  __syncthreads();
  sum = red[4] + red[5] + red[6] + red[7];
  if (t < LLEN) alpha[b * LLEN + t] = e / sum;
}

// ---------------------------------------------------------------------------
// K4: context from fp32 enc. Grid (2 f-chunks, 128 b, 4 L-chunks of 49), atomic.
__global__ void context_kernel(const float* __restrict__ enc, const float* __restrict__ alpha,
                               float* __restrict__ out) {
  __shared__ float al[49];
  int b = blockIdx.y, t = threadIdx.x;
  int l0 = blockIdx.z * 49;
  int f4 = blockIdx.x * 256 + t;
  if (t < 49) al[t] = alpha[b * LLEN + l0 + t];
  __syncthreads();
  const float4* e4 = (const float4*)enc + ((size_t)b * LLEN + l0) * (F_DIM / 4) + f4;
  float4 acc = {0.f, 0.f, 0.f, 0.f};
  #pragma unroll 7
  for (int l = 0; l < 49; ++l) {
    float4 v = e4[(size_t)l * (F_DIM / 4)];
    float a = al[l];
    acc.x = fmaf(v.x, a, acc.x);
    acc.y = fmaf(v.y, a, acc.y);
    acc.z = fmaf(v.z, a, acc.z);
    acc.w = fmaf(v.w, a, acc.w);
  }
  float* o = out + (size_t)b * F_DIM + f4 * 4;
  atomicAdd(o + 0, acc.x);
  atomicAdd(o + 1, acc.y);
  atomicAdd(o + 2, acc.z);
  atomicAdd(o + 3, acc.w);
}

// ---------------------------------------------------------------------------
extern "C" void kernel_launch(void* const* d_in, const int* in_sizes, int n_in,
                              void* d_out, int out_size, void* d_ws, size_t ws_size,
                              hipStream_t stream) {
  const float* enc    = (const float*)d_in[0];
  const float* hidden = (const float*)d_in[1];
  const float* W_enc  = (const float*)d_in[2];
  const float* b_enc  = (const float*)d_in[3];
  const float* W_hid  = (const float*)d_in[4];
  const float* b_hid  = (const float*)d_in[5];
  const float* W_full = (const float*)d_in[6];
  float* out = (float*)d_out;
  float* alpha_out = out + (size_t)BATCH * F_DIM;

  const size_t wt_bytes = (size_t)A_DIM * F_DIM * sizeof(u16);     // 4 MB
  const size_t a2_bytes = (size_t)BATCH * A_DIM * sizeof(float);   // 512 KB
  const size_t sc_bytes = (size_t)MROWS * sizeof(float);           // 100 KB
  char* ws = (char*)d_ws;
  u16*   WT     = (u16*)ws;
  float* attn2p = (float*)(ws + wt_bytes);
  float* scores = (float*)(ws + wt_bytes + a2_bytes);

  hipMemsetAsync(attn2p, 0, a2_bytes, stream);
  hipMemsetAsync(scores, 0, sc_bytes, stream);
  hipMemsetAsync(out, 0, (size_t)BATCH * F_DIM * sizeof(float), stream);

  wenc_cvt_kernel<<<dim3(F_DIM / 32, A_DIM / 32), 256, 0, stream>>>(W_enc, WT);
  attn2_kernel<<<dim3(A_DIM / 256, BATCH / 8, H_DIM / 128), 256, 0, stream>>>(hidden, W_hid, b_hid, b_enc, attn2p);
  gemm_score<<<dim3(1600), 256, 0, stream>>>(enc, WT, attn2p, W_full, scores);
  softmax_kernel<<<dim3(BATCH), 256, 0, stream>>>(scores, alpha_out);
  context_kernel<<<dim3(2, BATCH, 4), 256, 0, stream>>>(enc, alpha_out, out);
}